// Round 2
// baseline (1439.014 us; speedup 1.0000x reference)
//
#include <hip/hip_runtime.h>
#include <hip/hip_bf16.h>

typedef __bf16 bf16;
typedef bf16 bf16x8 __attribute__((ext_vector_type(8)));
typedef bf16 bf16x4 __attribute__((ext_vector_type(4)));
typedef float floatx4 __attribute__((ext_vector_type(4)));

#define LDS_STRIDE 136            // 128 + 8 bf16 pad: 16B-aligned, breaks pow2 bank stride
#define TILE_ROWS  64
#define TILE_ELEMS (TILE_ROWS * LDS_STRIDE)

// ---------------------------------------------------------------------------
// Repack weights: fp32 [K][N] row-major -> bf16 [N][K] (transposed) so that
// MFMA B-fragments (8 contiguous k per lane) are single 16B global loads.
// ---------------------------------------------------------------------------
__global__ void repack_weights(const float* __restrict__ W0,
                               const float* __restrict__ W1,
                               const float* __restrict__ W2,
                               bf16* __restrict__ Wt0,
                               bf16* __restrict__ Wt1,
                               bf16* __restrict__ Wt2) {
    int t = blockIdx.x * blockDim.x + threadIdx.x;
    const int S0 = 384 * 128, S1 = 128 * 128;
    if (t < S0) {
        int k = t >> 7, n = t & 127;
        Wt0[n * 384 + k] = (bf16)W0[t];
    } else if (t < S0 + S1) {
        int i = t - S0;
        int k = i >> 7, n = i & 127;
        Wt1[n * 128 + k] = (bf16)W1[i];
    } else if (t < S0 + 2 * S1) {
        int i = t - S0 - S1;
        int k = i >> 7, n = i & 127;
        Wt2[n * 128 + k] = (bf16)W2[i];
    }
}

// ---------------------------------------------------------------------------
// Fused 3-layer MLP, persistent blocks, software-pipelined staging.
// Block = 256 threads (4 waves), tile = 64 rows x 128 cols.
// Wave (wm,wn): rows wm*32..+31, cols wn*64..+63  -> acc[2][4] (32 VGPRs).
// Double-buffered LDS: chunk c0->BB, c1->BA, c2->BB, h0->BA, h1->BB,
// next-tile c0->BA; buffers swap roles each tile (sel ^= 1).
// Every global read is issued one full gemm phase before its LDS write.
// ---------------------------------------------------------------------------
__global__ __launch_bounds__(256, 4) void edge_mlp(
        const float* __restrict__ src,
        const float* __restrict__ dest,
        const float* __restrict__ edge_attr,
        const bf16* __restrict__ Wt0,
        const bf16* __restrict__ Wt1,
        const bf16* __restrict__ Wt2,
        const float* __restrict__ b0,
        const float* __restrict__ b1,
        const float* __restrict__ b2,
        float* __restrict__ out,
        int E) {
    __shared__ bf16 lds[2 * TILE_ELEMS];   // 34,816 B total (two 64x128 tiles)

    const int tid  = threadIdx.x;
    const int wave = tid >> 6;
    const int lane = tid & 63;
    const int wm   = wave >> 1;       // 0..1 : 32-row half
    const int wn   = wave & 1;        // 0..1 : 64-col half
    const int l15  = lane & 15;
    const int quad = lane >> 4;       // 0..3

    const long ntiles   = ((long)E + TILE_ROWS - 1) / TILE_ROWS;
    const long stride_t = gridDim.x;

    // ---- bias preload (per-thread, col n = wn*64 + j*16 + l15) ----
    float bv0[4], bv1[4], bv2[4];
#pragma unroll
    for (int j = 0; j < 4; ++j) {
        int n = wn * 64 + j * 16 + l15;
        bv0[j] = b0[n]; bv1[j] = b1[n]; bv2[j] = b2[n];
    }

    // staging coordinates: 256 threads cover 8 rows x 128 cols per pass
    const int sr = tid >> 5;          // 0..7
    const int sc = (tid & 31) * 4;    // 0,4,...,124

    float4 pf[8];                     // 32 VGPRs of in-flight staging data

    auto pf_load = [&](const float* __restrict__ xin, long t) {
        const long row0 = t * TILE_ROWS;
        if (row0 + TILE_ROWS <= (long)E) {
#pragma unroll
            for (int it = 0; it < 8; ++it)
                pf[it] = *(const float4*)(xin + (row0 + it * 8 + sr) * 128 + sc);
        } else {
#pragma unroll
            for (int it = 0; it < 8; ++it) {
                long gr = row0 + it * 8 + sr;
                if (gr >= 0 && gr < (long)E) pf[it] = *(const float4*)(xin + gr * 128 + sc);
                else                         pf[it] = make_float4(0.f, 0.f, 0.f, 0.f);
            }
        }
    };

    auto pf_store = [&](bf16* __restrict__ B) {
#pragma unroll
        for (int it = 0; it < 8; ++it) {
            int r = it * 8 + sr;
            bf16x4 bv;
            bv[0] = (bf16)pf[it].x; bv[1] = (bf16)pf[it].y;
            bv[2] = (bf16)pf[it].z; bv[3] = (bf16)pf[it].w;
            *(bf16x4*)&B[r * LDS_STRIDE + sc] = bv;
        }
    };

    const floatx4 zero4 = {0.f, 0.f, 0.f, 0.f};
    floatx4 acc[2][4];

    auto gemm_tile = [&](const bf16* __restrict__ B, const bf16* __restrict__ Wt,
                         int wstride, int kofs) {
#pragma unroll
        for (int ks = 0; ks < 4; ++ks) {
            const int kk = ks * 32 + quad * 8;
            bf16x8 a[2], b[4];
#pragma unroll
            for (int i = 0; i < 2; ++i)
                a[i] = *(const bf16x8*)&B[(wm * 32 + i * 16 + l15) * LDS_STRIDE + kk];
#pragma unroll
            for (int j = 0; j < 4; ++j)
                b[j] = *(const bf16x8*)(Wt + (wn * 64 + j * 16 + l15) * wstride + kofs + kk);
#pragma unroll
            for (int i = 0; i < 2; ++i)
#pragma unroll
                for (int j = 0; j < 4; ++j)
                    acc[i][j] = __builtin_amdgcn_mfma_f32_16x16x32_bf16(
                        a[i], b[j], acc[i][j], 0, 0, 0);
        }
    };

    auto epilogue_silu = [&](bf16* __restrict__ H, const float* bv) {
#pragma unroll
        for (int j = 0; j < 4; ++j) {
            int n = wn * 64 + j * 16 + l15;
#pragma unroll
            for (int i = 0; i < 2; ++i) {
                int rb = wm * 32 + i * 16 + quad * 4;
#pragma unroll
                for (int q = 0; q < 4; ++q) {
                    float x = acc[i][j][q] + bv[j];
                    float s = x / (1.f + __expf(-x));
                    H[(rb + q) * LDS_STRIDE + n] = (bf16)s;
                }
                acc[i][j] = zero4;
            }
        }
    };

    long t = blockIdx.x;
    if (t >= ntiles) return;

    // ---- prologue: first tile's chunk0 (edge_attr) into lds[0] ----
    pf_load(edge_attr, t);
    pf_store(lds);
    int sel = 0;
    __syncthreads();

    for (; t < ntiles; t += stride_t) {
        bf16* BB = lds + sel * TILE_ELEMS;        // holds chunk0 on entry
        bf16* BA = lds + (sel ^ 1) * TILE_ELEMS;

#pragma unroll
        for (int i = 0; i < 2; ++i)
#pragma unroll
            for (int j = 0; j < 4; ++j) acc[i][j] = zero4;

        // ---- layer 0, chunk pipeline (concat order: edge_attr, src, dest) ----
        pf_load(src, t);                       // c1 in flight during gemm(c0)
        gemm_tile(BB, Wt0, 384, 0);            // c0
        pf_store(BA);                          // c1 -> BA (waits its vmcnt only)
        pf_load(dest, t);                      // c2 in flight
        __syncthreads();                       // (1)

        gemm_tile(BA, Wt0, 384, 128);          // c1
        pf_store(BB);                          // c2 -> BB (readers drained at (1))
        pf_load(edge_attr, t + stride_t);      // NEXT tile's c0 in flight
        __syncthreads();                       // (2)

        gemm_tile(BB, Wt0, 384, 256);          // c2
        epilogue_silu(BA, bv0);                // h0 -> BA (readers drained at (2))
        __syncthreads();                       // (3)

        // ---- layer 1 ----
        gemm_tile(BA, Wt1, 128, 0);
        epilogue_silu(BB, bv1);                // h1 -> BB (readers drained at (3))
        __syncthreads();                       // (4)

        // ---- layer 2: no activation, fp32 store ----
        gemm_tile(BB, Wt2, 128, 0);
        const long row0 = t * TILE_ROWS;
        if (row0 + TILE_ROWS <= (long)E) {
#pragma unroll
            for (int j = 0; j < 4; ++j) {
                int n = wn * 64 + j * 16 + l15;
#pragma unroll
                for (int i = 0; i < 2; ++i) {
                    int rb = wm * 32 + i * 16 + quad * 4;
#pragma unroll
                    for (int q = 0; q < 4; ++q)
                        out[(row0 + rb + q) * 128 + n] = acc[i][j][q] + bv2[j];
                }
            }
        } else {
#pragma unroll
            for (int j = 0; j < 4; ++j) {
                int n = wn * 64 + j * 16 + l15;
#pragma unroll
                for (int i = 0; i < 2; ++i) {
                    int rb = wm * 32 + i * 16 + quad * 4;
#pragma unroll
                    for (int q = 0; q < 4; ++q) {
                        long gr = row0 + rb + q;
                        if (gr < (long)E) out[gr * 128 + n] = acc[i][j][q] + bv2[j];
                    }
                }
            }
        }
        pf_store(BA);                          // next c0 -> BA (readers drained at (4))
        __syncthreads();                       // (5)
        sel ^= 1;
    }
}

extern "C" void kernel_launch(void* const* d_in, const int* in_sizes, int n_in,
                              void* d_out, int out_size, void* d_ws, size_t ws_size,
                              hipStream_t stream) {
    const float* src       = (const float*)d_in[0];
    const float* dest      = (const float*)d_in[1];
    const float* edge_attr = (const float*)d_in[2];
    const float* W0        = (const float*)d_in[3];
    const float* b0        = (const float*)d_in[4];
    const float* W1        = (const float*)d_in[5];
    const float* b1        = (const float*)d_in[6];
    const float* W2        = (const float*)d_in[7];
    const float* b2        = (const float*)d_in[8];
    float*       out       = (float*)d_out;

    const int E = in_sizes[0] / 128;
    if (E <= 0) return;

    bf16* Wt0 = (bf16*)d_ws;            // [128][384] bf16 = 98,304 B
    bf16* Wt1 = Wt0 + 128 * 384;        // [128][128] bf16 = 32,768 B
    bf16* Wt2 = Wt1 + 128 * 128;        // [128][128] bf16 = 32,768 B

    repack_weights<<<(384 * 128 + 2 * 128 * 128 + 255) / 256, 256, 0, stream>>>(
        W0, W1, W2, Wt0, Wt1, Wt2);

    const long ntiles = ((long)E + TILE_ROWS - 1) / TILE_ROWS;
    const int  nblk   = (int)(ntiles < 2048 ? ntiles : 2048);
    edge_mlp<<<nblk, 256, 0, stream>>>(src, dest, edge_attr, Wt0, Wt1, Wt2,
                                       b0, b1, b2, out, E);
}